// Round 12
// baseline (443.121 us; speedup 1.0000x reference)
//
#include <hip/hip_runtime.h>
#include <hip/hip_bf16.h>

// SGConv (K=2) on MI355X.
// R4: MFMA matmul. R6: bucket build + counting sort -> CSR gather hops.
// R7: bf16 z-tables. R8: gather unroll + fused epilogue.
// R9 NEUTRAL: deeper unroll -> hops are LLC line-throughput-bound, not latency.
// R10/R11: column-split z into 16/16/8-col sub-tables (3.2/3.2/1.6 MB, each
//      fits a 4MB XCD L2); hop = 3 passes pinned to disjoint XCD sets via
//      bid&7. Gathers become XCD-local L2 hits. csr via nontemporal loads;
//      lsm un-fused back to its own kernel. (R11: fix nt-store vector type.)

#define TPB 256
#define ETILE 16384                // edges per partition block

typedef __attribute__((ext_vector_type(8))) short short8v;   // bf16x8
typedef __attribute__((ext_vector_type(4))) float f32x4;

__device__ inline short f2bf(float f) {            // RNE f32->bf16
    unsigned u = __float_as_uint(f);
    unsigned r = (u + 0x7fffu + ((u >> 16) & 1u)) >> 16;
    return (short)r;
}
__device__ inline float bf2f(short s) {
    return __uint_as_float(((unsigned)(unsigned short)s) << 16);
}

// ---- W -> Wb (48x512 bf16) and (block 0) zero bcnt ---------------------
__global__ void k_wconv(const float* __restrict__ W, short* __restrict__ Wb,
                        int* __restrict__ bcnt, int nb) {
    if (blockIdx.x == 0)
        for (int i = threadIdx.x; i < nb; i += TPB) bcnt[i] = 0;
    int idx = blockIdx.x * TPB + threadIdx.x;    // 0..24575
    int c = idx >> 9, k = idx & 511;
    float v = (c < 40) ? W[c * 512 + k] : 0.f;
    Wb[idx] = f2bf(v);
}

// ---- per-bucket edge histogram (bucket = dst>>8) -----------------------
__global__ __launch_bounds__(TPB) void k_bhist(
    const int* __restrict__ dst, int* __restrict__ bcnt, int E, int nb) {
    __shared__ int h[512];
    int t = threadIdx.x;
    for (int i = t; i < nb; i += TPB) h[i] = 0;
    __syncthreads();
    int e0 = blockIdx.x * ETILE;
    int e1 = min(e0 + ETILE, E);
    for (int e = e0 + t; e < e1; e += TPB)
        atomicAdd(&h[dst[e] >> 8], 1);
    __syncthreads();
    for (int i = t; i < nb; i += TPB)
        if (h[i]) atomicAdd(&bcnt[i], h[i]);
}

// ---- 391-entry exclusive scan -> boff, bcur (single block) -------------
__global__ __launch_bounds__(512) void k_boff(
    const int* __restrict__ bcnt, int* __restrict__ boff,
    int* __restrict__ bcur, int nb) {
    __shared__ int s[512];
    int t = threadIdx.x;
    int own = (t < nb) ? bcnt[t] : 0;
    s[t] = own;
    __syncthreads();
    for (int off = 1; off < 512; off <<= 1) {
        int v = (t >= off) ? s[t - off] : 0;
        __syncthreads();
        s[t] += v;
        __syncthreads();
    }
    if (t < nb) {
        int ex = s[t] - own;
        boff[t] = ex;
        bcur[t] = ex;
        if (t == nb - 1) boff[nb] = s[t];
    }
}

// ---- block-aggregated bucket partition (no stash: dst read twice) ------
__global__ __launch_bounds__(TPB) void k_part(
    const int* __restrict__ src, const int* __restrict__ dst,
    int* __restrict__ bcur, int* __restrict__ pairs, int E, int nb) {
    __shared__ int hist[512], base[512];
    int t = threadIdx.x;
    for (int i = t; i < nb; i += TPB) hist[i] = 0;
    __syncthreads();
    int e0 = blockIdx.x * ETILE;
    int e1 = min(e0 + ETILE, E);
    for (int e = e0 + t; e < e1; e += TPB)
        atomicAdd(&hist[dst[e] >> 8], 1);
    __syncthreads();
    for (int i = t; i < nb; i += TPB) {
        base[i] = hist[i] ? atomicAdd(&bcur[i], hist[i]) : 0;
        hist[i] = 0;                         // reuse as local cursor
    }
    __syncthreads();
    for (int e = e0 + t; e < e1; e += TPB) { // dst re-read: L2-warm
        int d = dst[e];
        int b = d >> 8;
        int pos = base[b] + atomicAdd(&hist[b], 1);
        pairs[pos] = ((d & 255) << 20) | src[e];   // src < 2^20
    }
}

// ---- per-bucket counting sort: pairs -> dst-sorted csr + row_ptr + dinv
__global__ __launch_bounds__(TPB) void k_sort(
    const int* __restrict__ pairs, const int* __restrict__ boff,
    int* __restrict__ csr, int* __restrict__ row_ptr, float* __restrict__ dinv,
    int N, int nb) {
    __shared__ int hist[256], excl[256], lcur[256];
    int b = blockIdx.x, t = threadIdx.x;
    hist[t] = 0;
    __syncthreads();
    int beg = boff[b], end = boff[b + 1];
    for (int j = beg + t; j < end; j += TPB)
        atomicAdd(&hist[pairs[j] >> 20], 1);
    __syncthreads();
    int own = hist[t];
    excl[t] = own;
    __syncthreads();
    for (int off = 1; off < 256; off <<= 1) {
        int v = (t >= off) ? excl[t - off] : 0;
        __syncthreads();
        excl[t] += v;
        __syncthreads();
    }
    int node = (b << 8) + t;
    if (node < N) {
        row_ptr[node] = beg + excl[t] - own;   // global exclusive offset
        dinv[node] = rsqrtf((float)(own + 1)); // +1 self-loop
    }
    lcur[t] = 0;
    __syncthreads();
    for (int j = beg + t; j < end; j += TPB) {
        int u = pairs[j];
        int dl = u >> 20;
        int pos = beg + (excl[dl] - hist[dl]) + atomicAdd(&lcur[dl], 1);
        csr[pos] = u & 0xFFFFF;
    }
    if (b == nb - 1 && t == 0) row_ptr[N] = end;
}

// ---- z0 = bf16( dinv .* (x @ W^T) ), column-split output ---------------
__global__ __launch_bounds__(TPB) void k_matmul_mfma(
    const float* __restrict__ x, const short* __restrict__ Wb,
    const float* __restrict__ dinv, short* __restrict__ zA,
    short* __restrict__ zB, short* __restrict__ zC, int N) {
    int wid  = threadIdx.x >> 6;
    int lane = threadIdx.x & 63;
    int rbase = blockIdx.x * 64 + wid * 16;
    if (rbase >= N) return;
    int arow   = rbase + (lane & 15);
    int aclamp = min(arow, N - 1);
    int koff   = (lane >> 4) * 8;
    const float* xrow = x + (size_t)aclamp * 512 + koff;
    const short* wb   = Wb + (lane & 15) * 512 + koff;

    f32x4 acc0 = {0.f,0.f,0.f,0.f}, acc1 = {0.f,0.f,0.f,0.f}, acc2 = {0.f,0.f,0.f,0.f};
    for (int ks = 0; ks < 16; ++ks) {
        int k0 = ks * 32;
        float4 f0 = *reinterpret_cast<const float4*>(xrow + k0);
        float4 f1 = *reinterpret_cast<const float4*>(xrow + k0 + 4);
        short8v a;
        a[0] = f2bf(f0.x); a[1] = f2bf(f0.y); a[2] = f2bf(f0.z); a[3] = f2bf(f0.w);
        a[4] = f2bf(f1.x); a[5] = f2bf(f1.y); a[6] = f2bf(f1.z); a[7] = f2bf(f1.w);
        short8v b0 = *reinterpret_cast<const short8v*>(wb + k0);
        short8v b1 = *reinterpret_cast<const short8v*>(wb + 16 * 512 + k0);
        short8v b2 = *reinterpret_cast<const short8v*>(wb + 32 * 512 + k0);
        acc0 = __builtin_amdgcn_mfma_f32_16x16x32_bf16(a, b0, acc0, 0, 0, 0);
        acc1 = __builtin_amdgcn_mfma_f32_16x16x32_bf16(a, b1, acc1, 0, 0, 0);
        acc2 = __builtin_amdgcn_mfma_f32_16x16x32_bf16(a, b2, acc2, 0, 0, 0);
    }
    int col = lane & 15;
    int rw  = rbase + (lane >> 4) * 4;
#pragma unroll
    for (int reg = 0; reg < 4; ++reg) {
        int r = rw + reg;
        if (r < N) {
            float di = dinv[r];
            zA[(size_t)r * 16 + col] = f2bf(di * acc0[reg]);
            zB[(size_t)r * 16 + col] = f2bf(di * acc1[reg]);
            if (col < 8)
                zC[(size_t)r * 8 + col] = f2bf(di * acc2[reg]);
        }
    }
}

// ---- fused 3-pass hop, XCD-pinned --------------------------------------
// Pass A (cols 0-15, zA, XCDs 0-2), B (16-31, zB, XCDs 3-5), C (32-39, zC,
// XCDs 6-7). Each sub-table <= 3.2 MB -> resident in its XCDs' L2.
// P==2 (hop1): zout_bf = bf16(dinv^2 * sum). P==1 (hop2): outf = dinv * sum.
template <int P>
__global__ __launch_bounds__(TPB) void k_hop_all(
    const int* __restrict__ csr, const int* __restrict__ row_ptr,
    const float* __restrict__ dinv,
    const short* __restrict__ zA, const short* __restrict__ zB,
    const short* __restrict__ zC,
    short* __restrict__ oA, short* __restrict__ oB, short* __restrict__ oC,
    float* __restrict__ outf, int N) {
    int bid = blockIdx.x;
    int x8 = bid & 7;
    int pass, pblk;
    if (x8 < 3)      { pass = 0; pblk = (bid >> 3) * 3 + x8; }
    else if (x8 < 6) { pass = 1; pblk = (bid >> 3) * 3 + (x8 - 3); }
    else             { pass = 2; pblk = (bid >> 3) * 2 + (x8 - 6); }
    int t = pblk * TPB + threadIdx.x;
    int node, c8, lpn;
    if (pass == 2) { node = t;      c8 = 0;     lpn = 1; }
    else           { node = t >> 1; c8 = t & 1; lpn = 2; }
    if (node >= N) return;
    const short* zin = (pass == 0) ? zA : (pass == 1) ? zB : zC;
    const short8v* Z = reinterpret_cast<const short8v*>(zin);
    int zi = node * lpn + c8;
    short8v sv = Z[zi];                        // self-loop term
    float acc[8];
#pragma unroll
    for (int k = 0; k < 8; ++k) acc[k] = bf2f(sv[k]);
    int beg = row_ptr[node];
    int end = row_ptr[node + 1];
    int j = beg;
    for (; j + 4 <= end; j += 4) {             // 4 gathers in flight
        int s0 = __builtin_nontemporal_load(csr + j);
        int s1 = __builtin_nontemporal_load(csr + j + 1);
        int s2 = __builtin_nontemporal_load(csr + j + 2);
        int s3 = __builtin_nontemporal_load(csr + j + 3);
        short8v v0 = Z[s0 * lpn + c8];
        short8v v1 = Z[s1 * lpn + c8];
        short8v v2 = Z[s2 * lpn + c8];
        short8v v3 = Z[s3 * lpn + c8];
#pragma unroll
        for (int k = 0; k < 8; ++k)
            acc[k] += (bf2f(v0[k]) + bf2f(v1[k])) + (bf2f(v2[k]) + bf2f(v3[k]));
    }
    for (; j < end; ++j) {
        short8v v = Z[__builtin_nontemporal_load(csr + j) * lpn + c8];
#pragma unroll
        for (int k = 0; k < 8; ++k) acc[k] += bf2f(v[k]);
    }
    float dd = dinv[node];
    if (P == 2) {
        float sc = dd * dd;
        short8v o;
#pragma unroll
        for (int k = 0; k < 8; ++k) o[k] = f2bf(sc * acc[k]);
        short* zo = (pass == 0) ? oA : (pass == 1) ? oB : oC;
        reinterpret_cast<short8v*>(zo)[zi] = o;
    } else {
        int off = (pass == 0) ? 0 : (pass == 1) ? 16 : 32;
        float* op = outf + (size_t)node * 40 + off + c8 * 8;
        f32x4 lo = {dd*acc[0], dd*acc[1], dd*acc[2], dd*acc[3]};
        f32x4 hi = {dd*acc[4], dd*acc[5], dd*acc[6], dd*acc[7]};
        __builtin_nontemporal_store(lo, reinterpret_cast<f32x4*>(op));
        __builtin_nontemporal_store(hi, reinterpret_cast<f32x4*>(op + 4));
    }
}

// ---- log_softmax rows (+bias), in place on d_out -----------------------
__global__ __launch_bounds__(TPB) void k_logsoftmax(
    float* __restrict__ out, const float* __restrict__ b, int N) {
    int r = blockIdx.x * TPB + threadIdx.x;
    if (r >= N) return;
    float4* rowp = reinterpret_cast<float4*>(out + (size_t)r * 40);
    float v[40];
    float m = -1e30f;
#pragma unroll
    for (int c4 = 0; c4 < 10; ++c4) {
        float4 t = rowp[c4];
        v[c4*4+0] = t.x + b[c4*4+0];
        v[c4*4+1] = t.y + b[c4*4+1];
        v[c4*4+2] = t.z + b[c4*4+2];
        v[c4*4+3] = t.w + b[c4*4+3];
    }
#pragma unroll
    for (int c = 0; c < 40; ++c) m = fmaxf(m, v[c]);
    float sum = 0.f;
#pragma unroll
    for (int c = 0; c < 40; ++c) sum += __expf(v[c] - m);
    float lse = m + __logf(sum);
#pragma unroll
    for (int c4 = 0; c4 < 10; ++c4)
        rowp[c4] = make_float4(v[c4*4+0]-lse, v[c4*4+1]-lse, v[c4*4+2]-lse, v[c4*4+3]-lse);
}

extern "C" void kernel_launch(void* const* d_in, const int* in_sizes, int n_in,
                              void* d_out, int out_size, void* d_ws, size_t ws_size,
                              hipStream_t stream) {
    const float* x  = (const float*)d_in[0];
    const int*   ei = (const int*)d_in[1];
    const float* W  = (const float*)d_in[2];
    const float* b  = (const float*)d_in[3];
    float* out = (float*)d_out;

    const int N = in_sizes[0] / 512;     // 100000
    const int E = in_sizes[1] / 2;       // 3200000
    const int* src = ei;                 // edge_index[0]
    const int* dst = ei + E;             // edge_index[1]
    const int nb = (N + 255) >> 8;       // 391 buckets

    // workspace: z0 split [N*16|N*16|N*8 bf16] | z1 split [same] | csr [E]
    //   | pairs [E] | bcnt [nb] | boff [nb+1] | bcur [nb] | row_ptr [N+1]
    //   | dinv [N] | Wb [48*512 bf16]   (~42 MB)
    short* zA0     = (short*)d_ws;
    short* zB0     = zA0 + (size_t)N * 16;
    short* zC0     = zB0 + (size_t)N * 16;
    short* zA1     = zC0 + (size_t)N * 8;
    short* zB1     = zA1 + (size_t)N * 16;
    short* zC1     = zB1 + (size_t)N * 16;
    int*   csr     = (int*)(zC1 + (size_t)N * 8);
    int*   pairs   = csr + E;
    int*   bcnt    = pairs + E;
    int*   boff    = bcnt + nb;
    int*   bcur    = boff + nb + 1;
    int*   row_ptr = bcur + nb;
    float* dinv    = (float*)(row_ptr + N + 1);
    short* Wb      = (short*)(dinv + N);

    int gT  = (E + ETILE - 1) / ETILE;   // 196 edge tiles
    int gM  = (N + 63) / 64;
    int gN  = (N + TPB - 1) / TPB;
    // fused hop grid: covers pass A (782 blks on bid%8<3), B (782 on 3..5),
    // C (391 on 6..7). Max needed bid = 2084.
    int gH  = 2085;

    k_wconv<<<(48 * 512) / TPB, TPB, 0, stream>>>(W, Wb, bcnt, nb);
    k_bhist<<<gT, TPB, 0, stream>>>(dst, bcnt, E, nb);
    k_boff<<<1, 512, 0, stream>>>(bcnt, boff, bcur, nb);
    k_part<<<gT, TPB, 0, stream>>>(src, dst, bcur, pairs, E, nb);
    k_sort<<<nb, TPB, 0, stream>>>(pairs, boff, csr, row_ptr, dinv, N, nb);

    k_matmul_mfma<<<gM, TPB, 0, stream>>>(x, Wb, dinv, zA0, zB0, zC0, N);

    k_hop_all<2><<<gH, TPB, 0, stream>>>(csr, row_ptr, dinv, zA0, zB0, zC0,
                                         zA1, zB1, zC1, nullptr, N);
    k_hop_all<1><<<gH, TPB, 0, stream>>>(csr, row_ptr, dinv, zA1, zB1, zC1,
                                         nullptr, nullptr, nullptr, out, N);

    k_logsoftmax<<<gN, TPB, 0, stream>>>(out, b, N);
}

// Round 13
// 310.676 us; speedup vs baseline: 1.4263x; 1.4263x over previous
//
#include <hip/hip_runtime.h>
#include <hip/hip_bf16.h>

// SGConv (K=2) on MI355X.
// R4: MFMA matmul. R6: bucket build + counting sort -> CSR gather hops.
// R7: bf16 z-tables. R8/R9: gather unroll + fused hop2/log_softmax.
// R11 FAILED: column-split tripled lines-touched-per-edge (FETCH 144MB/hop).
// R12: unified z padded to 64 bf16 cols = exactly ONE aligned 128B line per
//      gathered node (was ~1.5 lines for 80B rows); 8 lanes/node power-of-2
//      indexing; lsm reduce via shfl_xor over 8-lane groups, 64/64 active.

#define TPB 256
#define ETILE 16384                // edges per partition block
#define ZS 64                      // padded z row: 64 bf16 = 128 B

typedef __attribute__((ext_vector_type(8))) short short8v;   // bf16x8
typedef __attribute__((ext_vector_type(4))) float f32x4;

__device__ inline short f2bf(float f) {            // RNE f32->bf16
    unsigned u = __float_as_uint(f);
    unsigned r = (u + 0x7fffu + ((u >> 16) & 1u)) >> 16;
    return (short)r;
}
__device__ inline float bf2f(short s) {
    return __uint_as_float(((unsigned)(unsigned short)s) << 16);
}

// ---- W -> Wb (48x512 bf16) and (block 0) zero bcnt ---------------------
__global__ void k_wconv(const float* __restrict__ W, short* __restrict__ Wb,
                        int* __restrict__ bcnt, int nb) {
    if (blockIdx.x == 0)
        for (int i = threadIdx.x; i < nb; i += TPB) bcnt[i] = 0;
    int idx = blockIdx.x * TPB + threadIdx.x;    // 0..24575
    int c = idx >> 9, k = idx & 511;
    float v = (c < 40) ? W[c * 512 + k] : 0.f;
    Wb[idx] = f2bf(v);
}

// ---- per-bucket edge histogram (bucket = dst>>8) -----------------------
__global__ __launch_bounds__(TPB) void k_bhist(
    const int* __restrict__ dst, int* __restrict__ bcnt, int E, int nb) {
    __shared__ int h[512];
    int t = threadIdx.x;
    for (int i = t; i < nb; i += TPB) h[i] = 0;
    __syncthreads();
    int e0 = blockIdx.x * ETILE;
    int e1 = min(e0 + ETILE, E);
    for (int e = e0 + t; e < e1; e += TPB)
        atomicAdd(&h[dst[e] >> 8], 1);
    __syncthreads();
    for (int i = t; i < nb; i += TPB)
        if (h[i]) atomicAdd(&bcnt[i], h[i]);
}

// ---- 391-entry exclusive scan -> boff, bcur (single block) -------------
__global__ __launch_bounds__(512) void k_boff(
    const int* __restrict__ bcnt, int* __restrict__ boff,
    int* __restrict__ bcur, int nb) {
    __shared__ int s[512];
    int t = threadIdx.x;
    int own = (t < nb) ? bcnt[t] : 0;
    s[t] = own;
    __syncthreads();
    for (int off = 1; off < 512; off <<= 1) {
        int v = (t >= off) ? s[t - off] : 0;
        __syncthreads();
        s[t] += v;
        __syncthreads();
    }
    if (t < nb) {
        int ex = s[t] - own;
        boff[t] = ex;
        bcur[t] = ex;
        if (t == nb - 1) boff[nb] = s[t];
    }
}

// ---- block-aggregated bucket partition (no stash: dst read twice) ------
__global__ __launch_bounds__(TPB) void k_part(
    const int* __restrict__ src, const int* __restrict__ dst,
    int* __restrict__ bcur, int* __restrict__ pairs, int E, int nb) {
    __shared__ int hist[512], base[512];
    int t = threadIdx.x;
    for (int i = t; i < nb; i += TPB) hist[i] = 0;
    __syncthreads();
    int e0 = blockIdx.x * ETILE;
    int e1 = min(e0 + ETILE, E);
    for (int e = e0 + t; e < e1; e += TPB)
        atomicAdd(&hist[dst[e] >> 8], 1);
    __syncthreads();
    for (int i = t; i < nb; i += TPB) {
        base[i] = hist[i] ? atomicAdd(&bcur[i], hist[i]) : 0;
        hist[i] = 0;                         // reuse as local cursor
    }
    __syncthreads();
    for (int e = e0 + t; e < e1; e += TPB) { // dst re-read: L2-warm
        int d = dst[e];
        int b = d >> 8;
        int pos = base[b] + atomicAdd(&hist[b], 1);
        pairs[pos] = ((d & 255) << 20) | src[e];   // src < 2^20
    }
}

// ---- per-bucket counting sort: pairs -> dst-sorted csr + row_ptr + dinv
__global__ __launch_bounds__(TPB) void k_sort(
    const int* __restrict__ pairs, const int* __restrict__ boff,
    int* __restrict__ csr, int* __restrict__ row_ptr, float* __restrict__ dinv,
    int N, int nb) {
    __shared__ int hist[256], excl[256], lcur[256];
    int b = blockIdx.x, t = threadIdx.x;
    hist[t] = 0;
    __syncthreads();
    int beg = boff[b], end = boff[b + 1];
    for (int j = beg + t; j < end; j += TPB)
        atomicAdd(&hist[pairs[j] >> 20], 1);
    __syncthreads();
    int own = hist[t];
    excl[t] = own;
    __syncthreads();
    for (int off = 1; off < 256; off <<= 1) {
        int v = (t >= off) ? excl[t - off] : 0;
        __syncthreads();
        excl[t] += v;
        __syncthreads();
    }
    int node = (b << 8) + t;
    if (node < N) {
        row_ptr[node] = beg + excl[t] - own;   // global exclusive offset
        dinv[node] = rsqrtf((float)(own + 1)); // +1 self-loop
    }
    lcur[t] = 0;
    __syncthreads();
    for (int j = beg + t; j < end; j += TPB) {
        int u = pairs[j];
        int dl = u >> 20;
        int pos = beg + (excl[dl] - hist[dl]) + atomicAdd(&lcur[dl], 1);
        csr[pos] = u & 0xFFFFF;
    }
    if (b == nb - 1 && t == 0) row_ptr[N] = end;
}

// ---- z0 = bf16( dinv .* (x @ W^T) ), row stride 64, cols 40..63 = 0 ----
__global__ __launch_bounds__(TPB) void k_matmul_mfma(
    const float* __restrict__ x, const short* __restrict__ Wb,
    const float* __restrict__ dinv, short* __restrict__ z, int N) {
    int wid  = threadIdx.x >> 6;
    int lane = threadIdx.x & 63;
    int rbase = blockIdx.x * 64 + wid * 16;
    if (rbase >= N) return;
    int arow   = rbase + (lane & 15);
    int aclamp = min(arow, N - 1);
    int koff   = (lane >> 4) * 8;
    const float* xrow = x + (size_t)aclamp * 512 + koff;
    const short* wb   = Wb + (lane & 15) * 512 + koff;

    f32x4 acc0 = {0.f,0.f,0.f,0.f}, acc1 = {0.f,0.f,0.f,0.f}, acc2 = {0.f,0.f,0.f,0.f};
    for (int ks = 0; ks < 16; ++ks) {
        int k0 = ks * 32;
        float4 f0 = *reinterpret_cast<const float4*>(xrow + k0);
        float4 f1 = *reinterpret_cast<const float4*>(xrow + k0 + 4);
        short8v a;
        a[0] = f2bf(f0.x); a[1] = f2bf(f0.y); a[2] = f2bf(f0.z); a[3] = f2bf(f0.w);
        a[4] = f2bf(f1.x); a[5] = f2bf(f1.y); a[6] = f2bf(f1.z); a[7] = f2bf(f1.w);
        short8v b0 = *reinterpret_cast<const short8v*>(wb + k0);
        short8v b1 = *reinterpret_cast<const short8v*>(wb + 16 * 512 + k0);
        short8v b2 = *reinterpret_cast<const short8v*>(wb + 32 * 512 + k0);
        acc0 = __builtin_amdgcn_mfma_f32_16x16x32_bf16(a, b0, acc0, 0, 0, 0);
        acc1 = __builtin_amdgcn_mfma_f32_16x16x32_bf16(a, b1, acc1, 0, 0, 0);
        acc2 = __builtin_amdgcn_mfma_f32_16x16x32_bf16(a, b2, acc2, 0, 0, 0);
    }
    int col = lane & 15;
    int rw  = rbase + (lane >> 4) * 4;
#pragma unroll
    for (int reg = 0; reg < 4; ++reg) {
        int r = rw + reg;
        if (r < N) {
            float di = dinv[r];
            short* zr = z + (size_t)r * ZS;
            zr[col]      = f2bf(di * acc0[reg]);
            zr[16 + col] = f2bf(di * acc1[reg]);
            zr[32 + col] = f2bf(di * acc2[reg]);   // cols 40-47: Wb rows zero
            zr[48 + col] = 0;                      // cols 48-63: explicit zero
        }
    }
}

// ---- shared gather body: acc[8] += sum_{s in csr[beg..end)} zin[s] -----
// 8 lanes/node; each lane owns one 16B chunk of the 128B (one-line) row.
__device__ inline void gather_acc(
    const short8v* __restrict__ Z, const int* __restrict__ csr,
    int beg, int end, int c8, float acc[8]) {
    int j = beg;
    for (; j + 4 <= end; j += 4) {               // 4 gathers in flight
        int s0 = csr[j], s1 = csr[j+1], s2 = csr[j+2], s3 = csr[j+3];
        short8v v0 = Z[s0 * 8 + c8];
        short8v v1 = Z[s1 * 8 + c8];
        short8v v2 = Z[s2 * 8 + c8];
        short8v v3 = Z[s3 * 8 + c8];
#pragma unroll
        for (int k = 0; k < 8; ++k)
            acc[k] += (bf2f(v0[k]) + bf2f(v1[k])) + (bf2f(v2[k]) + bf2f(v3[k]));
    }
    for (; j < end; ++j) {
        short8v v = Z[csr[j] * 8 + c8];
#pragma unroll
        for (int k = 0; k < 8; ++k) acc[k] += bf2f(v[k]);
    }
}

// ---- hop1: z1 = bf16( dinv^2 .* (A z0) ), 8 lanes/node -----------------
__global__ __launch_bounds__(TPB) void k_hop1(
    const int* __restrict__ csr, const int* __restrict__ row_ptr,
    const float* __restrict__ dinv, const short* __restrict__ zin,
    short* __restrict__ zout, int N) {
    int t = blockIdx.x * TPB + threadIdx.x;
    int node = t >> 3;
    int c8 = t & 7;
    if (node >= N) return;
    const short8v* Z = reinterpret_cast<const short8v*>(zin);
    short8v sv = Z[node * 8 + c8];             // self-loop term
    float acc[8];
#pragma unroll
    for (int k = 0; k < 8; ++k) acc[k] = bf2f(sv[k]);
    gather_acc(Z, csr, row_ptr[node], row_ptr[node + 1], c8, acc);
    float dd = dinv[node];
    float sc = dd * dd;
    short8v o;
#pragma unroll
    for (int k = 0; k < 8; ++k) o[k] = f2bf(sc * acc[k]);
    reinterpret_cast<short8v*>(zout)[node * 8 + c8] = o;
}

// ---- hop2 fused with bias + log_softmax; 8 lanes/node, 8 nodes/wave ----
__global__ __launch_bounds__(TPB) void k_hop2_lsm(
    const int* __restrict__ csr, const int* __restrict__ row_ptr,
    const float* __restrict__ dinv, const short* __restrict__ zin,
    const float* __restrict__ bias, float* __restrict__ out, int N) {
    int t = blockIdx.x * TPB + threadIdx.x;
    int node = t >> 3;
    int c8 = t & 7;
    if (node >= N) return;
    const short8v* Z = reinterpret_cast<const short8v*>(zin);
    short8v sv = Z[node * 8 + c8];
    float acc[8];
#pragma unroll
    for (int k = 0; k < 8; ++k) acc[k] = bf2f(sv[k]);
    gather_acc(Z, csr, row_ptr[node], row_ptr[node + 1], c8, acc);
    float dd = dinv[node];

    float v[8];
    float lm = -1e30f;
    bool live = (c8 < 5);                      // cols 0..39 only
    if (live) {
#pragma unroll
        for (int k = 0; k < 8; ++k) {
            v[k] = dd * acc[k] + bias[c8 * 8 + k];
            lm = fmaxf(lm, v[k]);
        }
    }
    // butterfly over the 8-lane group (shfl_xor 1,2,4 stays in-group)
    float gm = lm;
    gm = fmaxf(gm, __shfl_xor(gm, 1));
    gm = fmaxf(gm, __shfl_xor(gm, 2));
    gm = fmaxf(gm, __shfl_xor(gm, 4));
    float ls = 0.f;
    if (live) {
#pragma unroll
        for (int k = 0; k < 8; ++k) ls += __expf(v[k] - gm);
    }
    ls += __shfl_xor(ls, 1);
    ls += __shfl_xor(ls, 2);
    ls += __shfl_xor(ls, 4);
    if (live) {
        float lse = gm + __logf(ls);
        float* op = out + (size_t)node * 40 + c8 * 8;
        *reinterpret_cast<float4*>(op)     = make_float4(v[0]-lse, v[1]-lse, v[2]-lse, v[3]-lse);
        *reinterpret_cast<float4*>(op + 4) = make_float4(v[4]-lse, v[5]-lse, v[6]-lse, v[7]-lse);
    }
}

extern "C" void kernel_launch(void* const* d_in, const int* in_sizes, int n_in,
                              void* d_out, int out_size, void* d_ws, size_t ws_size,
                              hipStream_t stream) {
    const float* x  = (const float*)d_in[0];
    const int*   ei = (const int*)d_in[1];
    const float* W  = (const float*)d_in[2];
    const float* b  = (const float*)d_in[3];
    float* out = (float*)d_out;

    const int N = in_sizes[0] / 512;     // 100000
    const int E = in_sizes[1] / 2;       // 3200000
    const int* src = ei;                 // edge_index[0]
    const int* dst = ei + E;             // edge_index[1]
    const int nb = (N + 255) >> 8;       // 391 buckets

    // workspace: z0 [N*64 bf16 = 12.8MB] | z1/pairs alias [12.8MB] | csr [E]
    //   | bcnt [nb] | boff [nb+1] | bcur [nb] | row_ptr [N+1] | dinv [N]
    //   | Wb [48*512 bf16]   (~39.3 MB total; pairs dead before hop1 writes z1)
    short* z0      = (short*)d_ws;
    short* z1      = z0 + (size_t)N * ZS;
    int*   pairs   = (int*)z1;                 // alias: dead after k_sort
    int*   csr     = (int*)(z1 + (size_t)N * ZS);
    int*   bcnt    = csr + E;
    int*   boff    = bcnt + nb;
    int*   bcur    = boff + nb + 1;
    int*   row_ptr = bcur + nb;
    float* dinv    = (float*)(row_ptr + N + 1);
    short* Wb      = (short*)(dinv + N);

    int gT  = (E + ETILE - 1) / ETILE;   // 196 edge tiles
    int gM  = (N + 63) / 64;
    int gH  = (N * 8 + TPB - 1) / TPB;   // 3125

    k_wconv<<<(48 * 512) / TPB, TPB, 0, stream>>>(W, Wb, bcnt, nb);
    k_bhist<<<gT, TPB, 0, stream>>>(dst, bcnt, E, nb);
    k_boff<<<1, 512, 0, stream>>>(bcnt, boff, bcur, nb);
    k_part<<<gT, TPB, 0, stream>>>(src, dst, bcur, pairs, E, nb);
    k_sort<<<nb, TPB, 0, stream>>>(pairs, boff, csr, row_ptr, dinv, N, nb);

    k_matmul_mfma<<<gM, TPB, 0, stream>>>(x, Wb, dinv, z0, N);

    k_hop1<<<gH, TPB, 0, stream>>>(csr, row_ptr, dinv, z0, z1, N);
    k_hop2_lsm<<<gH, TPB, 0, stream>>>(csr, row_ptr, dinv, z1, b, out, N);
}